// Round 6
// baseline (615.796 us; speedup 1.0000x reference)
//
#include <hip/hip_runtime.h>

// ---------------------------------------------------------------------------
// SAGE-GCN LSTM, N=1024, J=24, D=64.  R6 = occupancy + VALU surgery:
//  mono: 1024 blocks (4/CU!) x 512 thr (8 waves), 1 batch elem per block,
//   all 24 cells in-kernel. Per step: pre^T[256 x 24] = Wcat^T @ v^T via
//   32x32x16 bf16 MFMA; wave w owns M-tile w (64 W-VGPRs, persistent).
//   VALU cuts: v_rcp (no IEEE div), v_cvt_pk_bf16_f32 packing, sentinel
//   zero-row aggregation (no divergent branch).
//  dec: MFMA, 4-wave K-split + LDS reduce.  prep: weight packing.
// ---------------------------------------------------------------------------

typedef __bf16 bf16x8 __attribute__((ext_vector_type(8)));
typedef float f32x16 __attribute__((ext_vector_type(16)));

// neighbor table with sentinel 24 (zero row) instead of -1: always 5 reads
__constant__ int c_nbr2[24][5] = {
  {0,1,2,3,24},  {1,0,4,24,24}, {2,0,5,24,24}, {3,0,6,24,24},
  {4,1,7,24,24}, {5,2,8,24,24}, {6,3,9,24,24}, {7,4,10,24,24},
  {8,5,11,24,24},{9,6,12,13,14},{10,7,24,24,24},{11,8,24,24,24},
  {12,9,15,24,24},{13,9,16,24,24},{14,9,17,24,24},{15,12,24,24,24},
  {16,13,18,24,24},{17,14,19,24,24},{18,16,20,24,24},{19,17,21,24,24},
  {20,18,22,24,24},{21,19,23,24,24},{22,20,24,24,24},{23,21,24,24,24}
};
__constant__ float c_invdeg[24] = {
  0.25f, 1.f/3.f, 1.f/3.f, 1.f/3.f, 1.f/3.f, 1.f/3.f, 1.f/3.f, 1.f/3.f,
  1.f/3.f, 0.2f, 0.5f, 0.5f, 1.f/3.f, 1.f/3.f, 1.f/3.f, 0.5f,
  1.f/3.f, 1.f/3.f, 1.f/3.f, 1.f/3.f, 1.f/3.f, 1.f/3.f, 0.5f, 0.5f
};

__device__ __forceinline__ unsigned short f2b(float f) {   // fp32->bf16 RNE
  unsigned int u = __float_as_uint(f);
  u += 0x7fffu + ((u >> 16) & 1u);
  return (unsigned short)(u >> 16);
}
__device__ __forceinline__ unsigned pk2(float a, float b) {
  return (unsigned)f2b(a) | ((unsigned)f2b(b) << 16);
}
__device__ __forceinline__ unsigned cvtpk(float lo, float hi) {  // 1 inst
  unsigned r;
  asm("v_cvt_pk_bf16_f32 %0, %1, %2" : "=v"(r) : "v"(lo), "v"(hi));
  return r;
}
__device__ __forceinline__ float b2f_lo(unsigned u) { return __uint_as_float(u << 16); }
__device__ __forceinline__ float b2f_hi(unsigned u) { return __uint_as_float(u & 0xffff0000u); }
__device__ __forceinline__ float sigm_(float x) {
  return __builtin_amdgcn_rcpf(1.0f + __expf(-x));
}
__device__ __forceinline__ float tanh_(float x) {
  return 1.0f - 2.0f * __builtin_amdgcn_rcpf(1.0f + __expf(2.0f * x));
}

// ---------------------------------------------------------------------------
// prep: Wfrag = A-operand frag layout (gate-interleaved M), biasv, dec B-frags.
//  m32 (col within M-tile mt): gate g = m32&3, d = mt*8 + (m32>>2)
//  k = t*16 + (lane>>5)*8 + i; q=k>>6: q0 Wl[2g], q1 Wr[2g], q2 Wl[2g+1], q3 Wr[2g+1]
// ---------------------------------------------------------------------------
__global__ void prep3_kernel(const float* __restrict__ sWl, const float* __restrict__ sbl,
                             const float* __restrict__ sWr, const float* __restrict__ gb,
                             const float* __restrict__ dW,
                             unsigned short* __restrict__ Wfrag,
                             float* __restrict__ biasv,
                             unsigned short* __restrict__ Bdec)
{
  int id = blockIdx.x * 256 + threadIdx.x;          // 213248 total
  if (id < 65536) {                                  // Wfrag [mt][t][lane][8]
    int i = id & 7, l = (id >> 3) & 63, t = (id >> 9) & 15, mt = id >> 13;
    int m32 = l & 31;
    int g = m32 & 3, d = mt * 8 + (m32 >> 2);
    int k = t * 16 + ((l >> 5) << 3) + i;
    int q = k >> 6, kk = k & 63;
    const float* Ws = (q & 1) ? sWr : sWl;
    Wfrag[id] = f2b(Ws[((2 * g + (q >> 1)) * 64 + kk) * 64 + d]);
  } else if (id < 65792) {                           // biasv[mt*32 + m32]
    int c = id - 65536;
    int mt = c >> 5, m32 = c & 31;
    int g = m32 & 3, d = mt * 8 + (m32 >> 2);
    biasv[c] = sbl[(2 * g) * 64 + d] + sbl[(2 * g + 1) * 64 + d] + gb[g * 64 + d];
  } else {                                           // Bdec [nt][96 t][lane][8]
    int p = id - 65792;                              // < 147456
    int i = p & 7, l = (p >> 3) & 63;
    int rem = p >> 9;                                // nt*96 + t
    int nt = rem / 96, t = rem - nt * 96;
    int e = nt * 32 + (l & 31);
    int k = t * 16 + ((l >> 5) << 3) + i;
    Bdec[p] = (e < 72) ? f2b(dW[k * 72 + e]) : (unsigned short)0;
  }
}

// ---------------------------------------------------------------------------
// mono: all 24 cells for ONE batch element per block.  ~22.8 KB LDS -> 4/CU.
// ---------------------------------------------------------------------------
__global__ __launch_bounds__(512, 8) void mono6_kernel(
    const float* __restrict__ src, const float* __restrict__ tgt,
    const float* __restrict__ encW, const float* __restrict__ encb,
    const float* __restrict__ gw,
    const unsigned short* __restrict__ Wfrag,
    const float* __restrict__ biasv,
    unsigned short* __restrict__ obuf)
{
  __shared__ __align__(16) unsigned short Bf[16 * 64 * 8];   // 16 KB v-frags
  __shared__ __align__(16) unsigned short xs[25 * 64];       // 3.1 KB (+zero row)
  __shared__ __align__(16) unsigned short hs[25 * 64];       // 3.1 KB (+zero row)

  const int tid = threadIdx.x;
  const int n = blockIdx.x;
  const int w = tid >> 6, l = tid & 63;      // wave = M-tile mt
  const int l31 = l & 31, hi = l >> 5;

  // ---- persistent W: 1 M-tile x 16 k-steps = 64 VGPR ---------------------
  bf16x8 W[16];
  {
    const bf16x8* p0 = reinterpret_cast<const bf16x8*>(Wfrag) + (w * 16) * 64 + l;
    #pragma unroll
    for (int t = 0; t < 16; ++t) W[t] = p0[t * 64];
  }
  // ---- bias (bf16-packed per acc-reg pair), gate_w scalars ---------------
  unsigned bias_u[8];
  #pragma unroll
  for (int p = 0; p < 8; ++p) {
    int r0 = 2 * p, r1 = 2 * p + 1;
    int m0 = (r0 & 3) + 8 * (r0 >> 2) + 4 * hi;
    int m1 = (r1 & 3) + 8 * (r1 >> 2) + 4 * hi;
    bias_u[p] = pk2(biasv[w * 32 + m0], biasv[w * 32 + m1]);
  }
  float gwv[12];
  #pragma unroll
  for (int g = 0; g < 3; ++g)
    #pragma unroll
    for (int u = 0; u < 4; ++u)
      gwv[g * 4 + u] = gw[g * 64 + w * 8 + 2 * u + hi];

  float creg[4] = {0.f, 0.f, 0.f, 0.f};      // c-state for row l31, d = w*8+2u+hi

  // ---- zero init: h rows 0..24, x row 24, Bf pad rows 24..31 -------------
  for (int i = tid; i < 800; i += 512) reinterpret_cast<unsigned*>(hs)[i] = 0u;
  if (tid < 32) reinterpret_cast<unsigned*>(xs + 24 * 64)[tid] = 0u;
  if (tid < 256) {
    int t = tid >> 4, rest = tid & 15;
    int m = 24 + (rest & 7), h2 = rest >> 3;
    *reinterpret_cast<uint4*>(Bf + (t * 64 + m + (h2 << 5)) * 8) = make_uint4(0, 0, 0, 0);
  }

  auto enc_to_xs = [&](const float* frame) {
    #pragma unroll
    for (int ii = 0; ii < 3; ++ii) {
      int idx = tid + ii * 512;                 // < 1536
      int jj = idx >> 6, dd = idx & 63;
      const float* f = frame + jj * 3;
      float v = encb[dd] + f[0] * encW[dd] + f[1] * encW[64 + dd] + f[2] * encW[128 + dd];
      xs[jj * 64 + (((dd >> 3) ^ (jj & 7)) << 3) + (dd & 7)] = f2b(fmaxf(v, 0.0f));
    }
  };

  // v-build job bodies --------------------------------------------------------
  auto agg_job = [&](int job) {               // job in [0,384)
    int sec = job >= 192;
    int rem2 = job - sec * 192;
    int ch = (rem2 * 683) >> 14;              // /24
    int Mrow = rem2 - ch * 24;
    const unsigned short* sb = sec ? hs : xs;
    float s0 = 0, s1 = 0, s2 = 0, s3 = 0, s4 = 0, s5 = 0, s6 = 0, s7 = 0;
    #pragma unroll
    for (int m = 0; m < 5; ++m) {
      int nr = c_nbr2[Mrow][m];               // sentinel 24 = zero row
      uint4 u = *reinterpret_cast<const uint4*>(sb + nr * 64 + ((ch ^ (nr & 7)) << 3));
      s0 += b2f_lo(u.x); s1 += b2f_hi(u.x);
      s2 += b2f_lo(u.y); s3 += b2f_hi(u.y);
      s4 += b2f_lo(u.z); s5 += b2f_hi(u.z);
      s6 += b2f_lo(u.w); s7 += b2f_hi(u.w);
    }
    float sc = c_invdeg[Mrow];
    uint4 o;
    o.x = cvtpk(s0 * sc, s1 * sc); o.y = cvtpk(s2 * sc, s3 * sc);
    o.z = cvtpk(s4 * sc, s5 * sc); o.w = cvtpk(s6 * sc, s7 * sc);
    int kb = sec * 128 + ch * 8;
    int t = kb >> 4, h2 = ch & 1;
    *reinterpret_cast<uint4*>(Bf + ((t * 64) + Mrow + (h2 << 5)) * 8) = o;
  };
  auto copy_job = [&](int cj) {               // cj in [0,384)
    int sec = cj >= 192;
    int rem2 = cj - sec * 192;
    int ch = (rem2 * 683) >> 14;
    int Mrow = rem2 - ch * 24;
    const unsigned short* sb = sec ? hs : xs;
    uint4 u = *reinterpret_cast<const uint4*>(sb + Mrow * 64 + ((ch ^ (Mrow & 7)) << 3));
    int kb = 64 + sec * 128 + ch * 8;
    int t = kb >> 4, h2 = ch & 1;
    *reinterpret_cast<uint4*>(Bf + ((t * 64) + Mrow + (h2 << 5)) * 8) = u;
  };

  enc_to_xs(src + ((size_t)n * 16 + 4) * 72);   // warm-up starts at src frame 4
  __syncthreads();

  #pragma unroll 1
  for (int step = 0; step < 24; ++step) {
    if (step == 12) {                          // decode init: re-encode tgt[:,0]
      enc_to_xs(tgt + (size_t)n * 864);
      __syncthreads();
    }

    // ---- v-build: 768 jobs, wave-uniform split ---------------------------
    if (tid < 384) agg_job(tid);
    else           copy_job(tid - 384);        // cj 0..127
    if (tid < 256) copy_job(tid + 128);        // cj 128..383
    __syncthreads();

    // ---- GEMM: 16 MFMA, single acc chain ---------------------------------
    f32x16 acc;
    #pragma unroll
    for (int p = 0; p < 8; ++p) {
      acc[2 * p]     = b2f_lo(bias_u[p]);
      acc[2 * p + 1] = b2f_hi(bias_u[p]);
    }
    #pragma unroll
    for (int t = 0; t < 16; ++t) {
      bf16x8 vf = *reinterpret_cast<const bf16x8*>(Bf + (t * 64 + l) * 8);
      acc = __builtin_amdgcn_mfma_f32_32x32x16_bf16(W[t], vf, acc, 0, 0, 0);
    }

    // ---- lane-local epilogue: row l31 (<24), d = w*8 + 2u + hi -----------
    if (l31 < 24) {
      #pragma unroll
      for (int u = 0; u < 4; ++u) {
        float cv = creg[u];
        float I = sigm_(acc[4 * u + 0] + gwv[u] * cv);
        float F = sigm_(acc[4 * u + 1] + gwv[4 + u] * cv);
        float T = tanh_(acc[4 * u + 2]);
        float cn = F * cv + I * T;
        float O = sigm_(acc[4 * u + 3] + gwv[8 + u] * cn);
        float h = O * tanh_(cn);
        creg[u] = cn;
        unsigned oh = cvtpk(O, h);             // lo = bf16(O), hi = bf16(h)
        int d7 = 2 * u + hi;
        int off = l31 * 64 + ((w ^ (l31 & 7)) << 3) + d7;
        xs[off] = (unsigned short)oh;
        hs[off] = (unsigned short)(oh >> 16);
        if (step >= 12)
          obuf[(size_t)(n * 12 + step - 12) * 1536 + l31 * 64 + w * 8 + d7] =
              (unsigned short)oh;
      }
    }
    __syncthreads();
  }
}

// ---------------------------------------------------------------------------
// dec: out[row][e] = O[row,:] . decW[:,e] + db[e]; rows = n*12+ts.
// block: 32 rows, 4 waves K-split (384 each), 3 col-tiles, LDS reduce.
// ---------------------------------------------------------------------------
__global__ __launch_bounds__(256) void dec3_kernel(
    const unsigned short* __restrict__ obuf,
    const unsigned short* __restrict__ Bdec,
    const float* __restrict__ db,
    float* __restrict__ out)
{
  __shared__ float part[4 * 3 * 64 * 16];    // 48 KB
  const int tid = threadIdx.x;
  const int w = tid >> 6, l = tid & 63;
  const int l31 = l & 31, hi = l >> 5;
  const int r0 = blockIdx.x * 32;

  f32x16 a0, a1, a2;
  #pragma unroll
  for (int r = 0; r < 16; ++r) { a0[r] = 0.f; a1[r] = 0.f; a2[r] = 0.f; }

  const unsigned short* Ap = obuf + (size_t)(r0 + l31) * 1536 + hi * 8;
  #pragma unroll 4
  for (int tt = 0; tt < 24; ++tt) {
    int kt = w * 24 + tt;
    bf16x8 av = *reinterpret_cast<const bf16x8*>(Ap + kt * 16);
    bf16x8 b0 = *reinterpret_cast<const bf16x8*>(Bdec + ((0 * 96 + kt) * 64 + l) * 8);
    bf16x8 b1 = *reinterpret_cast<const bf16x8*>(Bdec + ((1 * 96 + kt) * 64 + l) * 8);
    bf16x8 b2 = *reinterpret_cast<const bf16x8*>(Bdec + ((2 * 96 + kt) * 64 + l) * 8);
    a0 = __builtin_amdgcn_mfma_f32_32x32x16_bf16(av, b0, a0, 0, 0, 0);
    a1 = __builtin_amdgcn_mfma_f32_32x32x16_bf16(av, b1, a1, 0, 0, 0);
    a2 = __builtin_amdgcn_mfma_f32_32x32x16_bf16(av, b2, a2, 0, 0, 0);
  }
  #pragma unroll
  for (int r = 0; r < 16; ++r) {
    part[((w * 3 + 0) * 64 + l) * 16 + r] = a0[r];
    part[((w * 3 + 1) * 64 + l) * 16 + r] = a1[r];
    part[((w * 3 + 2) * 64 + l) * 16 + r] = a2[r];
  }
  __syncthreads();

  // reduce 4 K-partials; thread -> (row = tid>>3, e = (tid&7)*12 + 0..11)
  int row = tid >> 3;
  int hi2 = (row >> 2) & 1;
  int rr = 4 * (row >> 3) + (row & 3);
  #pragma unroll
  for (int ei = 0; ei < 12; ++ei) {
    int e = (tid & 7) * 12 + ei;
    if (e < 72) {
      int nt = e >> 5, e32 = e & 31;
      float s = db[e];
      #pragma unroll
      for (int w2 = 0; w2 < 4; ++w2)
        s += part[((w2 * 3 + nt) * 64 + e32 + 32 * hi2) * 16 + rr];
      out[(size_t)(r0 + row) * 72 + e] = s;
    }
  }
}

// ---------------------------------------------------------------------------
extern "C" void kernel_launch(void* const* d_in, const int* in_sizes, int n_in,
                              void* d_out, int out_size, void* d_ws, size_t ws_size,
                              hipStream_t stream) {
  const float* src  = (const float*)d_in[0];   // [1024,16,72]
  const float* tgt  = (const float*)d_in[1];   // [1024,12,72]
  const float* encW = (const float*)d_in[2];   // [3,64]
  const float* encb = (const float*)d_in[3];   // [64]
  const float* sWl  = (const float*)d_in[4];   // [8,64,64]
  const float* sbl  = (const float*)d_in[5];   // [8,64]
  const float* sWr  = (const float*)d_in[6];   // [8,64,64]
  const float* gw   = (const float*)d_in[7];   // [3,1,64]
  const float* gb   = (const float*)d_in[8];   // [4,1,64]
  const float* dW   = (const float*)d_in[9];   // [1536,72]
  const float* db   = (const float*)d_in[10];  // [72]
  float* out = (float*)d_out;

  unsigned short* obuf  = (unsigned short*)d_ws;        // 12288*1536 bf16
  unsigned short* Wfrag = obuf + (size_t)12288 * 1536;  // 65536 bf16
  unsigned short* Bdec  = Wfrag + 65536;                // 147456 bf16
  float*          biasv = (float*)(Bdec + 147456);      // 256 f32

  prep3_kernel<<<833, 256, 0, stream>>>(sWl, sbl, sWr, gb, dW, Wfrag, biasv, Bdec);
  mono6_kernel<<<1024, 512, 0, stream>>>(src, tgt, encW, encb, gw, Wfrag, biasv, obuf);
  dec3_kernel<<<384, 256, 0, stream>>>(obuf, Bdec, db, out);
}

// Round 7
// 229.416 us; speedup vs baseline: 2.6842x; 2.6842x over previous
//
#include <hip/hip_runtime.h>

// ---------------------------------------------------------------------------
// SAGE-GCN LSTM, N=1024, J=24, D=64.  R7 = R6 structure + CORRECT launch
// bounds. __launch_bounds__(512, 4): 4 waves/EU min -> 128-VGPR cap -> the
// 64-VGPR persistent W tile fits (R5-proven); 2 blocks/CU (~50% occupancy).
// R6's (512,8) demanded 8 waves/EU -> 64-reg cap -> W spilled -> 1.96 GB
// scratch fetch, 605 us.
//  mono: 1024 blocks x 512 thr (8 waves), 1 batch elem per block, all 24
//   cells in-kernel. Per step: pre^T[256x24] = Wcat^T @ v^T via 32x32x16
//   bf16 MFMA; wave w owns M-tile w (64 W-VGPRs, persistent).
//   VALU cuts: v_rcp sigmoid/tanh, v_cvt_pk_bf16_f32, sentinel-row agg.
//  dec: MFMA, 4-wave K-split + LDS reduce.  prep: weight packing.
// ---------------------------------------------------------------------------

typedef __bf16 bf16x8 __attribute__((ext_vector_type(8)));
typedef float f32x16 __attribute__((ext_vector_type(16)));

// neighbor table with sentinel 24 (zero row) instead of -1: always 5 reads
__constant__ int c_nbr2[24][5] = {
  {0,1,2,3,24},  {1,0,4,24,24}, {2,0,5,24,24}, {3,0,6,24,24},
  {4,1,7,24,24}, {5,2,8,24,24}, {6,3,9,24,24}, {7,4,10,24,24},
  {8,5,11,24,24},{9,6,12,13,14},{10,7,24,24,24},{11,8,24,24,24},
  {12,9,15,24,24},{13,9,16,24,24},{14,9,17,24,24},{15,12,24,24,24},
  {16,13,18,24,24},{17,14,19,24,24},{18,16,20,24,24},{19,17,21,24,24},
  {20,18,22,24,24},{21,19,23,24,24},{22,20,24,24,24},{23,21,24,24,24}
};
__constant__ float c_invdeg[24] = {
  0.25f, 1.f/3.f, 1.f/3.f, 1.f/3.f, 1.f/3.f, 1.f/3.f, 1.f/3.f, 1.f/3.f,
  1.f/3.f, 0.2f, 0.5f, 0.5f, 1.f/3.f, 1.f/3.f, 1.f/3.f, 0.5f,
  1.f/3.f, 1.f/3.f, 1.f/3.f, 1.f/3.f, 1.f/3.f, 1.f/3.f, 0.5f, 0.5f
};

__device__ __forceinline__ unsigned short f2b(float f) {   // fp32->bf16 RNE
  unsigned int u = __float_as_uint(f);
  u += 0x7fffu + ((u >> 16) & 1u);
  return (unsigned short)(u >> 16);
}
__device__ __forceinline__ unsigned pk2(float a, float b) {
  return (unsigned)f2b(a) | ((unsigned)f2b(b) << 16);
}
__device__ __forceinline__ unsigned cvtpk(float lo, float hi) {  // 1 inst
  unsigned r;
  asm("v_cvt_pk_bf16_f32 %0, %1, %2" : "=v"(r) : "v"(lo), "v"(hi));
  return r;
}
__device__ __forceinline__ float b2f_lo(unsigned u) { return __uint_as_float(u << 16); }
__device__ __forceinline__ float b2f_hi(unsigned u) { return __uint_as_float(u & 0xffff0000u); }
__device__ __forceinline__ float sigm_(float x) {
  return __builtin_amdgcn_rcpf(1.0f + __expf(-x));
}
__device__ __forceinline__ float tanh_(float x) {
  return 1.0f - 2.0f * __builtin_amdgcn_rcpf(1.0f + __expf(2.0f * x));
}

// ---------------------------------------------------------------------------
// prep: Wfrag = A-operand frag layout (gate-interleaved M), biasv, dec B-frags.
//  m32 (col within M-tile mt): gate g = m32&3, d = mt*8 + (m32>>2)
//  k = t*16 + (lane>>5)*8 + i; q=k>>6: q0 Wl[2g], q1 Wr[2g], q2 Wl[2g+1], q3 Wr[2g+1]
// ---------------------------------------------------------------------------
__global__ void prep3_kernel(const float* __restrict__ sWl, const float* __restrict__ sbl,
                             const float* __restrict__ sWr, const float* __restrict__ gb,
                             const float* __restrict__ dW,
                             unsigned short* __restrict__ Wfrag,
                             float* __restrict__ biasv,
                             unsigned short* __restrict__ Bdec)
{
  int id = blockIdx.x * 256 + threadIdx.x;          // 213248 total
  if (id < 65536) {                                  // Wfrag [mt][t][lane][8]
    int i = id & 7, l = (id >> 3) & 63, t = (id >> 9) & 15, mt = id >> 13;
    int m32 = l & 31;
    int g = m32 & 3, d = mt * 8 + (m32 >> 2);
    int k = t * 16 + ((l >> 5) << 3) + i;
    int q = k >> 6, kk = k & 63;
    const float* Ws = (q & 1) ? sWr : sWl;
    Wfrag[id] = f2b(Ws[((2 * g + (q >> 1)) * 64 + kk) * 64 + d]);
  } else if (id < 65792) {                           // biasv[mt*32 + m32]
    int c = id - 65536;
    int mt = c >> 5, m32 = c & 31;
    int g = m32 & 3, d = mt * 8 + (m32 >> 2);
    biasv[c] = sbl[(2 * g) * 64 + d] + sbl[(2 * g + 1) * 64 + d] + gb[g * 64 + d];
  } else {                                           // Bdec [nt][96 t][lane][8]
    int p = id - 65792;                              // < 147456
    int i = p & 7, l = (p >> 3) & 63;
    int rem = p >> 9;                                // nt*96 + t
    int nt = rem / 96, t = rem - nt * 96;
    int e = nt * 32 + (l & 31);
    int k = t * 16 + ((l >> 5) << 3) + i;
    Bdec[p] = (e < 72) ? f2b(dW[k * 72 + e]) : (unsigned short)0;
  }
}

// ---------------------------------------------------------------------------
// mono: all 24 cells for ONE batch element per block.  ~22.8 KB LDS.
// __launch_bounds__(512, 4): 4 waves/EU -> 128-VGPR cap (no spill, 2 blk/CU).
// ---------------------------------------------------------------------------
__global__ __launch_bounds__(512, 4) void mono7_kernel(
    const float* __restrict__ src, const float* __restrict__ tgt,
    const float* __restrict__ encW, const float* __restrict__ encb,
    const float* __restrict__ gw,
    const unsigned short* __restrict__ Wfrag,
    const float* __restrict__ biasv,
    unsigned short* __restrict__ obuf)
{
  __shared__ __align__(16) unsigned short Bf[16 * 64 * 8];   // 16 KB v-frags
  __shared__ __align__(16) unsigned short xs[25 * 64];       // 3.1 KB (+zero row)
  __shared__ __align__(16) unsigned short hs[25 * 64];       // 3.1 KB (+zero row)

  const int tid = threadIdx.x;
  const int n = blockIdx.x;
  const int w = tid >> 6, l = tid & 63;      // wave = M-tile mt
  const int l31 = l & 31, hi = l >> 5;

  // ---- persistent W: 1 M-tile x 16 k-steps = 64 VGPR ---------------------
  bf16x8 W[16];
  {
    const bf16x8* p0 = reinterpret_cast<const bf16x8*>(Wfrag) + (w * 16) * 64 + l;
    #pragma unroll
    for (int t = 0; t < 16; ++t) W[t] = p0[t * 64];
  }
  // ---- bias (bf16-packed per acc-reg pair), gate_w scalars ---------------
  unsigned bias_u[8];
  #pragma unroll
  for (int p = 0; p < 8; ++p) {
    int r0 = 2 * p, r1 = 2 * p + 1;
    int m0 = (r0 & 3) + 8 * (r0 >> 2) + 4 * hi;
    int m1 = (r1 & 3) + 8 * (r1 >> 2) + 4 * hi;
    bias_u[p] = pk2(biasv[w * 32 + m0], biasv[w * 32 + m1]);
  }
  float gwv[12];
  #pragma unroll
  for (int g = 0; g < 3; ++g)
    #pragma unroll
    for (int u = 0; u < 4; ++u)
      gwv[g * 4 + u] = gw[g * 64 + w * 8 + 2 * u + hi];

  float creg[4] = {0.f, 0.f, 0.f, 0.f};      // c-state for row l31, d = w*8+2u+hi

  // ---- zero init: h rows 0..24, x row 24, Bf pad rows 24..31 -------------
  for (int i = tid; i < 800; i += 512) reinterpret_cast<unsigned*>(hs)[i] = 0u;
  if (tid < 32) reinterpret_cast<unsigned*>(xs + 24 * 64)[tid] = 0u;
  if (tid < 256) {
    int t = tid >> 4, rest = tid & 15;
    int m = 24 + (rest & 7), h2 = rest >> 3;
    *reinterpret_cast<uint4*>(Bf + (t * 64 + m + (h2 << 5)) * 8) = make_uint4(0, 0, 0, 0);
  }

  auto enc_to_xs = [&](const float* frame) {
    #pragma unroll
    for (int ii = 0; ii < 3; ++ii) {
      int idx = tid + ii * 512;                 // < 1536
      int jj = idx >> 6, dd = idx & 63;
      const float* f = frame + jj * 3;
      float v = encb[dd] + f[0] * encW[dd] + f[1] * encW[64 + dd] + f[2] * encW[128 + dd];
      xs[jj * 64 + (((dd >> 3) ^ (jj & 7)) << 3) + (dd & 7)] = f2b(fmaxf(v, 0.0f));
    }
  };

  // v-build job bodies --------------------------------------------------------
  auto agg_job = [&](int job) {               // job in [0,384)
    int sec = job >= 192;
    int rem2 = job - sec * 192;
    int ch = (rem2 * 683) >> 14;              // /24
    int Mrow = rem2 - ch * 24;
    const unsigned short* sb = sec ? hs : xs;
    float s0 = 0, s1 = 0, s2 = 0, s3 = 0, s4 = 0, s5 = 0, s6 = 0, s7 = 0;
    #pragma unroll
    for (int m = 0; m < 5; ++m) {
      int nr = c_nbr2[Mrow][m];               // sentinel 24 = zero row
      uint4 u = *reinterpret_cast<const uint4*>(sb + nr * 64 + ((ch ^ (nr & 7)) << 3));
      s0 += b2f_lo(u.x); s1 += b2f_hi(u.x);
      s2 += b2f_lo(u.y); s3 += b2f_hi(u.y);
      s4 += b2f_lo(u.z); s5 += b2f_hi(u.z);
      s6 += b2f_lo(u.w); s7 += b2f_hi(u.w);
    }
    float sc = c_invdeg[Mrow];
    uint4 o;
    o.x = cvtpk(s0 * sc, s1 * sc); o.y = cvtpk(s2 * sc, s3 * sc);
    o.z = cvtpk(s4 * sc, s5 * sc); o.w = cvtpk(s6 * sc, s7 * sc);
    int kb = sec * 128 + ch * 8;
    int t = kb >> 4, h2 = ch & 1;
    *reinterpret_cast<uint4*>(Bf + ((t * 64) + Mrow + (h2 << 5)) * 8) = o;
  };
  auto copy_job = [&](int cj) {               // cj in [0,384)
    int sec = cj >= 192;
    int rem2 = cj - sec * 192;
    int ch = (rem2 * 683) >> 14;
    int Mrow = rem2 - ch * 24;
    const unsigned short* sb = sec ? hs : xs;
    uint4 u = *reinterpret_cast<const uint4*>(sb + Mrow * 64 + ((ch ^ (Mrow & 7)) << 3));
    int kb = 64 + sec * 128 + ch * 8;
    int t = kb >> 4, h2 = ch & 1;
    *reinterpret_cast<uint4*>(Bf + ((t * 64) + Mrow + (h2 << 5)) * 8) = u;
  };

  enc_to_xs(src + ((size_t)n * 16 + 4) * 72);   // warm-up starts at src frame 4
  __syncthreads();

  #pragma unroll 1
  for (int step = 0; step < 24; ++step) {
    if (step == 12) {                          // decode init: re-encode tgt[:,0]
      enc_to_xs(tgt + (size_t)n * 864);
      __syncthreads();
    }

    // ---- v-build: 768 jobs, wave-uniform split ---------------------------
    if (tid < 384) agg_job(tid);
    else           copy_job(tid - 384);        // cj 0..127
    if (tid < 256) copy_job(tid + 128);        // cj 128..383
    __syncthreads();

    // ---- GEMM: 16 MFMA, single acc chain ---------------------------------
    f32x16 acc;
    #pragma unroll
    for (int p = 0; p < 8; ++p) {
      acc[2 * p]     = b2f_lo(bias_u[p]);
      acc[2 * p + 1] = b2f_hi(bias_u[p]);
    }
    #pragma unroll
    for (int t = 0; t < 16; ++t) {
      bf16x8 vf = *reinterpret_cast<const bf16x8*>(Bf + (t * 64 + l) * 8);
      acc = __builtin_amdgcn_mfma_f32_32x32x16_bf16(W[t], vf, acc, 0, 0, 0);
    }

    // ---- lane-local epilogue: row l31 (<24), d = w*8 + 2u + hi -----------
    if (l31 < 24) {
      #pragma unroll
      for (int u = 0; u < 4; ++u) {
        float cv = creg[u];
        float I = sigm_(acc[4 * u + 0] + gwv[u] * cv);
        float F = sigm_(acc[4 * u + 1] + gwv[4 + u] * cv);
        float T = tanh_(acc[4 * u + 2]);
        float cn = F * cv + I * T;
        float O = sigm_(acc[4 * u + 3] + gwv[8 + u] * cn);
        float h = O * tanh_(cn);
        creg[u] = cn;
        unsigned oh = cvtpk(O, h);             // lo = bf16(O), hi = bf16(h)
        int d7 = 2 * u + hi;
        int off = l31 * 64 + ((w ^ (l31 & 7)) << 3) + d7;
        xs[off] = (unsigned short)oh;
        hs[off] = (unsigned short)(oh >> 16);
        if (step >= 12)
          obuf[(size_t)(n * 12 + step - 12) * 1536 + l31 * 64 + w * 8 + d7] =
              (unsigned short)oh;
      }
    }
    __syncthreads();
  }
}

// ---------------------------------------------------------------------------
// dec: out[row][e] = O[row,:] . decW[:,e] + db[e]; rows = n*12+ts.
// block: 32 rows, 4 waves K-split (384 each), 3 col-tiles, LDS reduce.
// ---------------------------------------------------------------------------
__global__ __launch_bounds__(256) void dec3_kernel(
    const unsigned short* __restrict__ obuf,
    const unsigned short* __restrict__ Bdec,
    const float* __restrict__ db,
    float* __restrict__ out)
{
  __shared__ float part[4 * 3 * 64 * 16];    // 48 KB
  const int tid = threadIdx.x;
  const int w = tid >> 6, l = tid & 63;
  const int l31 = l & 31, hi = l >> 5;
  const int r0 = blockIdx.x * 32;

  f32x16 a0, a1, a2;
  #pragma unroll
  for (int r = 0; r < 16; ++r) { a0[r] = 0.f; a1[r] = 0.f; a2[r] = 0.f; }

  const unsigned short* Ap = obuf + (size_t)(r0 + l31) * 1536 + hi * 8;
  #pragma unroll 4
  for (int tt = 0; tt < 24; ++tt) {
    int kt = w * 24 + tt;
    bf16x8 av = *reinterpret_cast<const bf16x8*>(Ap + kt * 16);
    bf16x8 b0 = *reinterpret_cast<const bf16x8*>(Bdec + ((0 * 96 + kt) * 64 + l) * 8);
    bf16x8 b1 = *reinterpret_cast<const bf16x8*>(Bdec + ((1 * 96 + kt) * 64 + l) * 8);
    bf16x8 b2 = *reinterpret_cast<const bf16x8*>(Bdec + ((2 * 96 + kt) * 64 + l) * 8);
    a0 = __builtin_amdgcn_mfma_f32_32x32x16_bf16(av, b0, a0, 0, 0, 0);
    a1 = __builtin_amdgcn_mfma_f32_32x32x16_bf16(av, b1, a1, 0, 0, 0);
    a2 = __builtin_amdgcn_mfma_f32_32x32x16_bf16(av, b2, a2, 0, 0, 0);
  }
  #pragma unroll
  for (int r = 0; r < 16; ++r) {
    part[((w * 3 + 0) * 64 + l) * 16 + r] = a0[r];
    part[((w * 3 + 1) * 64 + l) * 16 + r] = a1[r];
    part[((w * 3 + 2) * 64 + l) * 16 + r] = a2[r];
  }
  __syncthreads();

  // reduce 4 K-partials; thread -> (row = tid>>3, e = (tid&7)*12 + 0..11)
  int row = tid >> 3;
  int hi2 = (row >> 2) & 1;
  int rr = 4 * (row >> 3) + (row & 3);
  #pragma unroll
  for (int ei = 0; ei < 12; ++ei) {
    int e = (tid & 7) * 12 + ei;
    if (e < 72) {
      int nt = e >> 5, e32 = e & 31;
      float s = db[e];
      #pragma unroll
      for (int w2 = 0; w2 < 4; ++w2)
        s += part[((w2 * 3 + nt) * 64 + e32 + 32 * hi2) * 16 + rr];
      out[(size_t)(r0 + row) * 72 + e] = s;
    }
  }
}

// ---------------------------------------------------------------------------
extern "C" void kernel_launch(void* const* d_in, const int* in_sizes, int n_in,
                              void* d_out, int out_size, void* d_ws, size_t ws_size,
                              hipStream_t stream) {
  const float* src  = (const float*)d_in[0];   // [1024,16,72]
  const float* tgt  = (const float*)d_in[1];   // [1024,12,72]
  const float* encW = (const float*)d_in[2];   // [3,64]
  const float* encb = (const float*)d_in[3];   // [64]
  const float* sWl  = (const float*)d_in[4];   // [8,64,64]
  const float* sbl  = (const float*)d_in[5];   // [8,64]
  const float* sWr  = (const float*)d_in[6];   // [8,64,64]
  const float* gw   = (const float*)d_in[7];   // [3,1,64]
  const float* gb   = (const float*)d_in[8];   // [4,1,64]
  const float* dW   = (const float*)d_in[9];   // [1536,72]
  const float* db   = (const float*)d_in[10];  // [72]
  float* out = (float*)d_out;

  unsigned short* obuf  = (unsigned short*)d_ws;        // 12288*1536 bf16
  unsigned short* Wfrag = obuf + (size_t)12288 * 1536;  // 65536 bf16
  unsigned short* Bdec  = Wfrag + 65536;                // 147456 bf16
  float*          biasv = (float*)(Bdec + 147456);      // 256 f32

  prep3_kernel<<<833, 256, 0, stream>>>(sWl, sbl, sWr, gb, dW, Wfrag, biasv, Bdec);
  mono7_kernel<<<1024, 512, 0, stream>>>(src, tgt, encW, encb, gw, Wfrag, biasv, obuf);
  dec3_kernel<<<384, 256, 0, stream>>>(obuf, Bdec, db, out);
}

// Round 8
// 218.994 us; speedup vs baseline: 2.8119x; 1.0476x over previous
//
#include <hip/hip_runtime.h>

// ---------------------------------------------------------------------------
// SAGE-GCN LSTM, N=1024, J=24, D=64.  R8 = fragment-resident state + 2 elems:
//  mono: 512 blocks (2/CU) x 512 thr (8 waves), 2 batch elems per block, all
//   24 cells in-kernel. x/h state lives directly in MFMA B-fragment layout:
//     k-tiles 0-3 = agg(x) [AGG buf], 4-7 = x [XH buf], 8-11 = agg(h) [AGG],
//     12-15 = h [XH].  XH double-buffered (epi writes buf^1 while GEMM reads
//   buf); AGG single-buffered. No copy jobs, no separate xs/hs, 2 barriers.
//   Per step, per elem: 16 MFMA (32x32x16 bf16), wave w owns M-tile w
//   (64 W-VGPRs persistent); elems sequential per wave (single acc chain,
//   ~115 live VGPRs < 128 cap from __launch_bounds__(512,4)).
//  dec: MFMA, 4-wave K-split + LDS reduce.  prep: weight packing.
// ---------------------------------------------------------------------------

typedef __bf16 bf16x8 __attribute__((ext_vector_type(8)));
typedef float f32x16 __attribute__((ext_vector_type(16)));

// neighbor table with sentinel 24 (zero pad row) instead of -1: always 5 reads
__constant__ int c_nbr2[24][5] = {
  {0,1,2,3,24},  {1,0,4,24,24}, {2,0,5,24,24}, {3,0,6,24,24},
  {4,1,7,24,24}, {5,2,8,24,24}, {6,3,9,24,24}, {7,4,10,24,24},
  {8,5,11,24,24},{9,6,12,13,14},{10,7,24,24,24},{11,8,24,24,24},
  {12,9,15,24,24},{13,9,16,24,24},{14,9,17,24,24},{15,12,24,24,24},
  {16,13,18,24,24},{17,14,19,24,24},{18,16,20,24,24},{19,17,21,24,24},
  {20,18,22,24,24},{21,19,23,24,24},{22,20,24,24,24},{23,21,24,24,24}
};
__constant__ float c_invdeg[24] = {
  0.25f, 1.f/3.f, 1.f/3.f, 1.f/3.f, 1.f/3.f, 1.f/3.f, 1.f/3.f, 1.f/3.f,
  1.f/3.f, 0.2f, 0.5f, 0.5f, 1.f/3.f, 1.f/3.f, 1.f/3.f, 0.5f,
  1.f/3.f, 1.f/3.f, 1.f/3.f, 1.f/3.f, 1.f/3.f, 1.f/3.f, 0.5f, 0.5f
};

__device__ __forceinline__ unsigned short f2b(float f) {   // fp32->bf16 RNE
  unsigned int u = __float_as_uint(f);
  u += 0x7fffu + ((u >> 16) & 1u);
  return (unsigned short)(u >> 16);
}
__device__ __forceinline__ unsigned pk2(float a, float b) {
  return (unsigned)f2b(a) | ((unsigned)f2b(b) << 16);
}
__device__ __forceinline__ unsigned cvtpk(float lo, float hi) {  // 1 inst
  unsigned r;
  asm("v_cvt_pk_bf16_f32 %0, %1, %2" : "=v"(r) : "v"(lo), "v"(hi));
  return r;
}
__device__ __forceinline__ float b2f_lo(unsigned u) { return __uint_as_float(u << 16); }
__device__ __forceinline__ float b2f_hi(unsigned u) { return __uint_as_float(u & 0xffff0000u); }
__device__ __forceinline__ float sigm_(float x) {
  return __builtin_amdgcn_rcpf(1.0f + __expf(-x));
}
__device__ __forceinline__ float tanh_(float x) {
  return 1.0f - 2.0f * __builtin_amdgcn_rcpf(1.0f + __expf(2.0f * x));
}

// ---------------------------------------------------------------------------
// prep: Wfrag = A-operand frag layout (gate-interleaved M), biasv, dec B-frags.
//  m32 (col within M-tile mt): gate g = m32&3, d = mt*8 + (m32>>2)
//  k = t*16 + (lane>>5)*8 + i; q=k>>6: q0 Wl[2g], q1 Wr[2g], q2 Wl[2g+1], q3 Wr[2g+1]
// ---------------------------------------------------------------------------
__global__ void prep3_kernel(const float* __restrict__ sWl, const float* __restrict__ sbl,
                             const float* __restrict__ sWr, const float* __restrict__ gb,
                             const float* __restrict__ dW,
                             unsigned short* __restrict__ Wfrag,
                             float* __restrict__ biasv,
                             unsigned short* __restrict__ Bdec)
{
  int id = blockIdx.x * 256 + threadIdx.x;          // 213248 total
  if (id < 65536) {                                  // Wfrag [mt][t][lane][8]
    int i = id & 7, l = (id >> 3) & 63, t = (id >> 9) & 15, mt = id >> 13;
    int m32 = l & 31;
    int g = m32 & 3, d = mt * 8 + (m32 >> 2);
    int k = t * 16 + ((l >> 5) << 3) + i;
    int q = k >> 6, kk = k & 63;
    const float* Ws = (q & 1) ? sWr : sWl;
    Wfrag[id] = f2b(Ws[((2 * g + (q >> 1)) * 64 + kk) * 64 + d]);
  } else if (id < 65792) {                           // biasv[mt*32 + m32]
    int c = id - 65536;
    int mt = c >> 5, m32 = c & 31;
    int g = m32 & 3, d = mt * 8 + (m32 >> 2);
    biasv[c] = sbl[(2 * g) * 64 + d] + sbl[(2 * g + 1) * 64 + d] + gb[g * 64 + d];
  } else {                                           // Bdec [nt][96 t][lane][8]
    int p = id - 65792;                              // < 147456
    int i = p & 7, l = (p >> 3) & 63;
    int rem = p >> 9;                                // nt*96 + t
    int nt = rem / 96, t = rem - nt * 96;
    int e = nt * 32 + (l & 31);
    int k = t * 16 + ((l >> 5) << 3) + i;
    Bdec[p] = (e < 72) ? f2b(dW[k * 72 + e]) : (unsigned short)0;
  }
}

// ---------------------------------------------------------------------------
// mono: all 24 cells for TWO batch elements per block.  48 KB LDS, 2 blk/CU.
// ---------------------------------------------------------------------------
__global__ __launch_bounds__(512, 4) void mono8_kernel(
    const float* __restrict__ src, const float* __restrict__ tgt,
    const float* __restrict__ encW, const float* __restrict__ encb,
    const float* __restrict__ gw,
    const unsigned short* __restrict__ Wfrag,
    const float* __restrict__ biasv,
    unsigned short* __restrict__ obuf)
{
  // frag-layout state. Slot s holds rows(lanes) 0..23 + zero pad 24..31,
  // element addr = (slot*64 + row + khalf*32)*8 + i  (u16), 16B per (row,chunk).
  __shared__ __align__(16) unsigned short AGG[2][8 * 64 * 8];     // 16 KB: [e], slots 0-3 agg(x), 4-7 agg(h)
  __shared__ __align__(16) unsigned short XH[2][2][8 * 64 * 8];   // 32 KB: [buf][e], slots 0-3 x, 4-7 h

  const int tid = threadIdx.x;
  const int n2 = blockIdx.x * 2;
  const int w = tid >> 6, l = tid & 63;      // wave = M-tile mt
  const int l31 = l & 31, hi = l >> 5;

  // ---- persistent W: 1 M-tile x 16 k-steps = 64 VGPR ---------------------
  bf16x8 W[16];
  {
    const bf16x8* p0 = reinterpret_cast<const bf16x8*>(Wfrag) + (w * 16) * 64 + l;
    #pragma unroll
    for (int t = 0; t < 16; ++t) W[t] = p0[t * 64];
  }
  // ---- bias (bf16-packed per acc-reg pair), gate_w scalars ---------------
  unsigned bias_u[8];
  #pragma unroll
  for (int p = 0; p < 8; ++p) {
    int r0 = 2 * p, r1 = 2 * p + 1;
    int m0 = (r0 & 3) + 8 * (r0 >> 2) + 4 * hi;
    int m1 = (r1 & 3) + 8 * (r1 >> 2) + 4 * hi;
    bias_u[p] = pk2(biasv[w * 32 + m0], biasv[w * 32 + m1]);
  }
  float gwv[12];
  #pragma unroll
  for (int g = 0; g < 3; ++g)
    #pragma unroll
    for (int u = 0; u < 4; ++u)
      gwv[g * 4 + u] = gw[g * 64 + w * 8 + 2 * u + hi];

  float creg[8];                             // c-state: [e][u], fp32
  #pragma unroll
  for (int i = 0; i < 8; ++i) creg[i] = 0.0f;

  // ---- zero init: XH both bufs (h=0 + pad rows), AGG pad rows ------------
  {
    uint4 z = make_uint4(0, 0, 0, 0);
    uint4* xz = reinterpret_cast<uint4*>(&XH[0][0][0]);
    #pragma unroll
    for (int i = 0; i < 4; ++i) xz[tid + i * 512] = z;       // 2048 uint4 = 32 KB
    uint4* az = reinterpret_cast<uint4*>(&AGG[0][0]);
    #pragma unroll
    for (int i = 0; i < 2; ++i) az[tid + i * 512] = z;       // 1024 uint4 = 16 KB
  }

  // encoder -> x-sections (slots 0-3) of XH[buf]
  auto enc_to_x = [&](const float* f0, const float* f1, int buf) {
    #pragma unroll
    for (int ii = 0; ii < 6; ++ii) {
      int idx = tid + ii * 512;               // < 3072
      int e = (idx >= 1536) ? 1 : 0;
      int r = idx - e * 1536;
      int j = r >> 6, d = r & 63;
      const float* f = (e ? f1 : f0) + j * 3;
      float v = encb[d] + f[0] * encW[d] + f[1] * encW[64 + d] + f[2] * encW[128 + d];
      XH[buf][e][((d >> 4) * 64 + j + ((d >> 3) & 1) * 32) * 8 + (d & 7)] =
          f2b(fmaxf(v, 0.0f));
    }
  };

  // aggregation job: jb in [0,768) = e*384 + sec*192 + ch*24 + Mrow
  auto agg_job = [&](int jb, int cur) {
    int e = (jb >= 384) ? 1 : 0;
    int r = jb - e * 384;
    int sec = (r >= 192) ? 1 : 0;
    int r2 = r - sec * 192;
    int ch = (r2 * 683) >> 14;                // r2 / 24
    int Mrow = r2 - ch * 24;
    int sbase = (sec * 4 + (ch >> 1)) * 64 + ((ch & 1) << 5);   // row-0 base
    const unsigned short* xh = &XH[cur][e][0];
    float s0 = 0, s1 = 0, s2 = 0, s3 = 0, s4 = 0, s5 = 0, s6 = 0, s7 = 0;
    #pragma unroll
    for (int m = 0; m < 5; ++m) {
      int nr = c_nbr2[Mrow][m];               // sentinel 24 = zero pad row
      uint4 u = *reinterpret_cast<const uint4*>(xh + (sbase + nr) * 8);
      s0 += b2f_lo(u.x); s1 += b2f_hi(u.x);
      s2 += b2f_lo(u.y); s3 += b2f_hi(u.y);
      s4 += b2f_lo(u.z); s5 += b2f_hi(u.z);
      s6 += b2f_lo(u.w); s7 += b2f_hi(u.w);
    }
    float sc = c_invdeg[Mrow];
    uint4 o;
    o.x = cvtpk(s0 * sc, s1 * sc); o.y = cvtpk(s2 * sc, s3 * sc);
    o.z = cvtpk(s4 * sc, s5 * sc); o.w = cvtpk(s6 * sc, s7 * sc);
    *reinterpret_cast<uint4*>(&AGG[e][0] + (sbase + Mrow) * 8) = o;
  };

  enc_to_x(src + ((size_t)n2 * 16 + 4) * 72,
           src + ((size_t)(n2 + 1) * 16 + 4) * 72, 0);   // warm-up frame 4
  __syncthreads();

  int cur = 0;
  #pragma unroll 1
  for (int step = 0; step < 24; ++step) {
    if (step == 12) {                          // decode init: re-encode tgt[:,0]
      enc_to_x(tgt + (size_t)n2 * 864, tgt + (size_t)(n2 + 1) * 864, cur);
      __syncthreads();
    }

    // ---- Phase A: aggregation (768 jobs) ---------------------------------
    agg_job(tid, cur);
    if (tid < 256) agg_job(tid + 512, cur);
    __syncthreads();

    // ---- Phase B: per elem GEMM + lane-local epilogue --------------------
    #pragma unroll
    for (int e = 0; e < 2; ++e) {
      const unsigned short* aggb = &AGG[e][0];
      const unsigned short* xhb  = &XH[cur][e][0];
      f32x16 acc;
      #pragma unroll
      for (int p = 0; p < 8; ++p) {
        acc[2 * p]     = b2f_lo(bias_u[p]);
        acc[2 * p + 1] = b2f_hi(bias_u[p]);
      }
      #pragma unroll
      for (int t = 0; t < 4; ++t)              // k 0..63: agg(x)
        acc = __builtin_amdgcn_mfma_f32_32x32x16_bf16(
            W[t], *reinterpret_cast<const bf16x8*>(aggb + (t * 64 + l) * 8), acc, 0, 0, 0);
      #pragma unroll
      for (int t = 0; t < 4; ++t)              // k 64..127: x
        acc = __builtin_amdgcn_mfma_f32_32x32x16_bf16(
            W[4 + t], *reinterpret_cast<const bf16x8*>(xhb + (t * 64 + l) * 8), acc, 0, 0, 0);
      #pragma unroll
      for (int t = 0; t < 4; ++t)              // k 128..191: agg(h)
        acc = __builtin_amdgcn_mfma_f32_32x32x16_bf16(
            W[8 + t], *reinterpret_cast<const bf16x8*>(aggb + ((4 + t) * 64 + l) * 8), acc, 0, 0, 0);
      #pragma unroll
      for (int t = 0; t < 4; ++t)              // k 192..255: h
        acc = __builtin_amdgcn_mfma_f32_32x32x16_bf16(
            W[12 + t], *reinterpret_cast<const bf16x8*>(xhb + ((4 + t) * 64 + l) * 8), acc, 0, 0, 0);

      if (l31 < 24) {                          // epilogue: row l31, d = w*8+2u+hi
        unsigned short* xw = &XH[cur ^ 1][e][0];
        const int wb = ((w >> 1) * 64 + l31 + ((w & 1) << 5)) * 8;
        #pragma unroll
        for (int u = 0; u < 4; ++u) {
          float cv = creg[e * 4 + u];
          float I = sigm_(acc[4 * u + 0] + gwv[u] * cv);
          float F = sigm_(acc[4 * u + 1] + gwv[4 + u] * cv);
          float T = tanh_(acc[4 * u + 2]);
          float cn = F * cv + I * T;
          float O = sigm_(acc[4 * u + 3] + gwv[8 + u] * cn);
          float h = O * tanh_(cn);
          creg[e * 4 + u] = cn;
          unsigned oh = cvtpk(O, h);           // lo = bf16(O), hi = bf16(h)
          int d7 = 2 * u + hi;
          xw[wb + d7]        = (unsigned short)oh;         // x slot (w>>1)
          xw[2048 + wb + d7] = (unsigned short)(oh >> 16); // h slot 4+(w>>1)
          if (step >= 12)
            obuf[(size_t)((n2 + e) * 12 + step - 12) * 1536 + l31 * 64 + w * 8 + d7] =
                (unsigned short)oh;
        }
      }
    }
    __syncthreads();
    cur ^= 1;
  }
}

// ---------------------------------------------------------------------------
// dec: out[row][e] = O[row,:] . decW[:,e] + db[e]; rows = n*12+ts.
// block: 32 rows, 4 waves K-split (384 each), 3 col-tiles, LDS reduce.
// ---------------------------------------------------------------------------
__global__ __launch_bounds__(256) void dec3_kernel(
    const unsigned short* __restrict__ obuf,
    const unsigned short* __restrict__ Bdec,
    const float* __restrict__ db,
    float* __restrict__ out)
{
  __shared__ float part[4 * 3 * 64 * 16];    // 48 KB
  const int tid = threadIdx.x;
  const int w = tid >> 6, l = tid & 63;
  const int l31 = l & 31, hi = l >> 5;
  const int r0 = blockIdx.x * 32;

  f32x16 a0, a1, a2;
  #pragma unroll
  for (int r = 0; r < 16; ++r) { a0[r] = 0.f; a1[r] = 0.f; a2[r] = 0.f; }

  const unsigned short* Ap = obuf + (size_t)(r0 + l31) * 1536 + hi * 8;
  #pragma unroll 4
  for (int tt = 0; tt < 24; ++tt) {
    int kt = w * 24 + tt;
    bf16x8 av = *reinterpret_cast<const bf16x8*>(Ap + kt * 16);
    bf16x8 b0 = *reinterpret_cast<const bf16x8*>(Bdec + ((0 * 96 + kt) * 64 + l) * 8);
    bf16x8 b1 = *reinterpret_cast<const bf16x8*>(Bdec + ((1 * 96 + kt) * 64 + l) * 8);
    bf16x8 b2 = *reinterpret_cast<const bf16x8*>(Bdec + ((2 * 96 + kt) * 64 + l) * 8);
    a0 = __builtin_amdgcn_mfma_f32_32x32x16_bf16(av, b0, a0, 0, 0, 0);
    a1 = __builtin_amdgcn_mfma_f32_32x32x16_bf16(av, b1, a1, 0, 0, 0);
    a2 = __builtin_amdgcn_mfma_f32_32x32x16_bf16(av, b2, a2, 0, 0, 0);
  }
  #pragma unroll
  for (int r = 0; r < 16; ++r) {
    part[((w * 3 + 0) * 64 + l) * 16 + r] = a0[r];
    part[((w * 3 + 1) * 64 + l) * 16 + r] = a1[r];
    part[((w * 3 + 2) * 64 + l) * 16 + r] = a2[r];
  }
  __syncthreads();

  // reduce 4 K-partials; thread -> (row = tid>>3, e = (tid&7)*12 + 0..11)
  int row = tid >> 3;
  int hi2 = (row >> 2) & 1;
  int rr = 4 * (row >> 3) + (row & 3);
  #pragma unroll
  for (int ei = 0; ei < 12; ++ei) {
    int e = (tid & 7) * 12 + ei;
    if (e < 72) {
      int nt = e >> 5, e32 = e & 31;
      float s = db[e];
      #pragma unroll
      for (int w2 = 0; w2 < 4; ++w2)
        s += part[((w2 * 3 + nt) * 64 + e32 + 32 * hi2) * 16 + rr];
      out[(size_t)(r0 + row) * 72 + e] = s;
    }
  }
}

// ---------------------------------------------------------------------------
extern "C" void kernel_launch(void* const* d_in, const int* in_sizes, int n_in,
                              void* d_out, int out_size, void* d_ws, size_t ws_size,
                              hipStream_t stream) {
  const float* src  = (const float*)d_in[0];   // [1024,16,72]
  const float* tgt  = (const float*)d_in[1];   // [1024,12,72]
  const float* encW = (const float*)d_in[2];   // [3,64]
  const float* encb = (const float*)d_in[3];   // [64]
  const float* sWl  = (const float*)d_in[4];   // [8,64,64]
  const float* sbl  = (const float*)d_in[5];   // [8,64]
  const float* sWr  = (const float*)d_in[6];   // [8,64,64]
  const float* gw   = (const float*)d_in[7];   // [3,1,64]
  const float* gb   = (const float*)d_in[8];   // [4,1,64]
  const float* dW   = (const float*)d_in[9];   // [1536,72]
  const float* db   = (const float*)d_in[10];  // [72]
  float* out = (float*)d_out;

  unsigned short* obuf  = (unsigned short*)d_ws;        // 12288*1536 bf16
  unsigned short* Wfrag = obuf + (size_t)12288 * 1536;  // 65536 bf16
  unsigned short* Bdec  = Wfrag + 65536;                // 147456 bf16
  float*          biasv = (float*)(Bdec + 147456);      // 256 f32

  prep3_kernel<<<833, 256, 0, stream>>>(sWl, sbl, sWr, gb, dW, Wfrag, biasv, Bdec);
  mono8_kernel<<<512, 512, 0, stream>>>(src, tgt, encW, encb, gw, Wfrag, biasv, obuf);
  dec3_kernel<<<384, 256, 0, stream>>>(obuf, Bdec, db, out);
}

// Round 9
// 203.697 us; speedup vs baseline: 3.0231x; 1.0751x over previous
//
#include <hip/hip_runtime.h>

// ---------------------------------------------------------------------------
// SAGE-GCN LSTM, N=1024, J=24, D=64.  R9 = elem-pipelined phases + fp16:
//  mono: 512 blocks (2/CU) x 512 thr (8 waves), 2 elems/block, 24 cells.
//   Per step (2 barriers):
//     P1: GEMM(e0)+epi(e0)  ||  agg(e1, this step)     [independent streams]
//     P2: GEMM(e1)+epi(e1)  ||  agg(e0, next step)
//   State x/h in MFMA B-frag layout (fp16), XH double-buffered, AGG single.
//   All data fp16 (v_pk_add_f16 aggregation, mfma_f32_32x32x16_f16); c-state
//   and gate math fp32 in regs; wave w owns M-tile w (64 W-VGPRs persistent).
//  dec: fp16 MFMA, 4-wave K-split + LDS reduce.  prep: weight packing.
// ---------------------------------------------------------------------------

typedef _Float16 f16x8 __attribute__((ext_vector_type(8)));
typedef float f32x16 __attribute__((ext_vector_type(16)));

// neighbor table with sentinel 24 (zero pad row) instead of -1: always 5 reads
__constant__ int c_nbr2[24][5] = {
  {0,1,2,3,24},  {1,0,4,24,24}, {2,0,5,24,24}, {3,0,6,24,24},
  {4,1,7,24,24}, {5,2,8,24,24}, {6,3,9,24,24}, {7,4,10,24,24},
  {8,5,11,24,24},{9,6,12,13,14},{10,7,24,24,24},{11,8,24,24,24},
  {12,9,15,24,24},{13,9,16,24,24},{14,9,17,24,24},{15,12,24,24,24},
  {16,13,18,24,24},{17,14,19,24,24},{18,16,20,24,24},{19,17,21,24,24},
  {20,18,22,24,24},{21,19,23,24,24},{22,20,24,24,24},{23,21,24,24,24}
};
__constant__ float c_invdeg[24] = {
  0.25f, 1.f/3.f, 1.f/3.f, 1.f/3.f, 1.f/3.f, 1.f/3.f, 1.f/3.f, 1.f/3.f,
  1.f/3.f, 0.2f, 0.5f, 0.5f, 1.f/3.f, 1.f/3.f, 1.f/3.f, 0.5f,
  1.f/3.f, 1.f/3.f, 1.f/3.f, 1.f/3.f, 1.f/3.f, 1.f/3.f, 0.5f, 0.5f
};

__device__ __forceinline__ unsigned short f2h(float f) {
  _Float16 h = (_Float16)f;
  return __builtin_bit_cast(unsigned short, h);
}
__device__ __forceinline__ unsigned pk2h(float a, float b) {
  return (unsigned)f2h(a) | ((unsigned)f2h(b) << 16);
}
__device__ __forceinline__ unsigned pkrtz(float lo, float hi) {  // 1 inst
  unsigned r;
  asm("v_cvt_pkrtz_f16_f32 %0, %1, %2" : "=v"(r) : "v"(lo), "v"(hi));
  return r;
}
__device__ __forceinline__ float h2f_lo(unsigned u) {
  return (float)__builtin_bit_cast(_Float16, (unsigned short)(u & 0xffff));
}
__device__ __forceinline__ float h2f_hi(unsigned u) {
  return (float)__builtin_bit_cast(_Float16, (unsigned short)(u >> 16));
}
__device__ __forceinline__ float sigm_(float x) {
  return __builtin_amdgcn_rcpf(1.0f + __expf(-x));
}
__device__ __forceinline__ float tanh_(float x) {
  return 1.0f - 2.0f * __builtin_amdgcn_rcpf(1.0f + __expf(2.0f * x));
}

// ---------------------------------------------------------------------------
// prep: Wfrag (fp16, A-frag layout, gate-interleaved M), biasv f32, Bdec fp16.
//  m32: gate g = m32&3, d = mt*8 + (m32>>2)
//  k = t*16 + (lane>>5)*8 + i; q=k>>6: q0 Wl[2g], q1 Wr[2g], q2 Wl[2g+1], q3 Wr[2g+1]
// ---------------------------------------------------------------------------
__global__ void prep4_kernel(const float* __restrict__ sWl, const float* __restrict__ sbl,
                             const float* __restrict__ sWr, const float* __restrict__ gb,
                             const float* __restrict__ dW,
                             unsigned short* __restrict__ Wfrag,
                             float* __restrict__ biasv,
                             unsigned short* __restrict__ Bdec)
{
  int id = blockIdx.x * 256 + threadIdx.x;          // 213248 total
  if (id < 65536) {                                  // Wfrag [mt][t][lane][8]
    int i = id & 7, l = (id >> 3) & 63, t = (id >> 9) & 15, mt = id >> 13;
    int m32 = l & 31;
    int g = m32 & 3, d = mt * 8 + (m32 >> 2);
    int k = t * 16 + ((l >> 5) << 3) + i;
    int q = k >> 6, kk = k & 63;
    const float* Ws = (q & 1) ? sWr : sWl;
    Wfrag[id] = f2h(Ws[((2 * g + (q >> 1)) * 64 + kk) * 64 + d]);
  } else if (id < 65792) {                           // biasv[mt*32 + m32]
    int c = id - 65536;
    int mt = c >> 5, m32 = c & 31;
    int g = m32 & 3, d = mt * 8 + (m32 >> 2);
    biasv[c] = sbl[(2 * g) * 64 + d] + sbl[(2 * g + 1) * 64 + d] + gb[g * 64 + d];
  } else {                                           // Bdec [nt][96 t][lane][8]
    int p = id - 65792;                              // < 147456
    int i = p & 7, l = (p >> 3) & 63;
    int rem = p >> 9;                                // nt*96 + t
    int nt = rem / 96, t = rem - nt * 96;
    int e = nt * 32 + (l & 31);
    int k = t * 16 + ((l >> 5) << 3) + i;
    Bdec[p] = (e < 72) ? f2h(dW[k * 72 + e]) : (unsigned short)0;
  }
}

// ---------------------------------------------------------------------------
// mono: all 24 cells for TWO batch elements per block, pipelined phases.
// ---------------------------------------------------------------------------
__global__ __launch_bounds__(512, 4) void mono9_kernel(
    const float* __restrict__ src, const float* __restrict__ tgt,
    const float* __restrict__ encW, const float* __restrict__ encb,
    const float* __restrict__ gw,
    const unsigned short* __restrict__ Wfrag,
    const float* __restrict__ biasv,
    unsigned short* __restrict__ obuf)
{
  // frag-layout state. addr (u16) = (slot*64 + row + khalf*32)*8 + i.
  __shared__ __align__(16) unsigned short AGG[2][8 * 64 * 8];     // 16 KB
  __shared__ __align__(16) unsigned short XH[2][2][8 * 64 * 8];   // 32 KB

  const int tid = threadIdx.x;
  const int n2 = blockIdx.x * 2;
  const int w = tid >> 6, l = tid & 63;      // wave = M-tile mt
  const int l31 = l & 31, hi = l >> 5;

  // ---- persistent W: 1 M-tile x 16 k-steps = 64 VGPR ---------------------
  f16x8 W[16];
  {
    const f16x8* p0 = reinterpret_cast<const f16x8*>(Wfrag) + (w * 16) * 64 + l;
    #pragma unroll
    for (int t = 0; t < 16; ++t) W[t] = p0[t * 64];
  }
  // ---- bias (fp16-packed per acc-reg pair), gate_w scalars ---------------
  unsigned bias_u[8];
  #pragma unroll
  for (int p = 0; p < 8; ++p) {
    int r0 = 2 * p, r1 = 2 * p + 1;
    int m0 = (r0 & 3) + 8 * (r0 >> 2) + 4 * hi;
    int m1 = (r1 & 3) + 8 * (r1 >> 2) + 4 * hi;
    bias_u[p] = pk2h(biasv[w * 32 + m0], biasv[w * 32 + m1]);
  }
  float gwv[12];
  #pragma unroll
  for (int g = 0; g < 3; ++g)
    #pragma unroll
    for (int u = 0; u < 4; ++u)
      gwv[g * 4 + u] = gw[g * 64 + w * 8 + 2 * u + hi];

  float creg[8];                             // c-state: [e][u]
  #pragma unroll
  for (int i = 0; i < 8; ++i) creg[i] = 0.0f;

  // ---- zero init ---------------------------------------------------------
  {
    uint4 z = make_uint4(0, 0, 0, 0);
    uint4* xz = reinterpret_cast<uint4*>(&XH[0][0][0]);
    #pragma unroll
    for (int i = 0; i < 4; ++i) xz[tid + i * 512] = z;
    uint4* az = reinterpret_cast<uint4*>(&AGG[0][0]);
    #pragma unroll
    for (int i = 0; i < 2; ++i) az[tid + i * 512] = z;
  }

  // encoder -> x-sections (slots 0-3) of XH[buf]
  auto enc_to_x = [&](const float* f0, const float* f1, int buf) {
    #pragma unroll
    for (int ii = 0; ii < 6; ++ii) {
      int idx = tid + ii * 512;               // < 3072
      int e = (idx >= 1536) ? 1 : 0;
      int r = idx - e * 1536;
      int j = r >> 6, d = r & 63;
      const float* f = (e ? f1 : f0) + j * 3;
      float v = encb[d] + f[0] * encW[d] + f[1] * encW[64 + d] + f[2] * encW[128 + d];
      XH[buf][e][((d >> 4) * 64 + j + ((d >> 3) & 1) * 32) * 8 + (d & 7)] =
          f2h(fmaxf(v, 0.0f));
    }
  };

  // aggregation job: jb in [0,384) = sec*192 + ch*24 + Mrow, for elem e
  auto agg_job = [&](int jb, int e, int srcbuf) {
    int sec = (jb >= 192) ? 1 : 0;
    int r2 = jb - sec * 192;
    int ch = (r2 * 683) >> 14;                // r2 / 24
    int Mrow = r2 - ch * 24;
    int sbase = (sec * 4 + (ch >> 1)) * 64 + ((ch & 1) << 5);   // row-0 base
    const unsigned short* xh = &XH[srcbuf][e][0];
    f16x8 s0 = *reinterpret_cast<const f16x8*>(xh + (sbase + c_nbr2[Mrow][0]) * 8);
    #pragma unroll
    for (int m = 1; m < 5; ++m) {             // sentinel 24 = zero pad row
      s0 += *reinterpret_cast<const f16x8*>(xh + (sbase + c_nbr2[Mrow][m]) * 8);
    }
    s0 *= (_Float16)c_invdeg[Mrow];
    *reinterpret_cast<f16x8*>(&AGG[e][0] + (sbase + Mrow) * 8) = s0;
  };

  int cur = 0;

  enc_to_x(src + ((size_t)n2 * 16 + 4) * 72,
           src + ((size_t)(n2 + 1) * 16 + 4) * 72, 0);   // warm-up frame 4
  __syncthreads();
  if (tid < 384) agg_job(tid, 0, 0);          // prologue: agg(e0, step 0)
  __syncthreads();

  // phase: GEMM+epi for elem eg, overlapped with agg for elem ea
  auto phase = [&](int eg, int ea, int aggsrc, int step) {
    const unsigned short* aggb = &AGG[eg][0];
    const unsigned short* xhb  = &XH[cur][eg][0];
    f32x16 acc;
    #pragma unroll
    for (int p = 0; p < 8; ++p) {
      acc[2 * p]     = h2f_lo(bias_u[p]);
      acc[2 * p + 1] = h2f_hi(bias_u[p]);
    }
    #pragma unroll
    for (int t = 0; t < 4; ++t)               // k 0..63: agg(x)
      acc = __builtin_amdgcn_mfma_f32_32x32x16_f16(
          W[t], *reinterpret_cast<const f16x8*>(aggb + (t * 64 + l) * 8), acc, 0, 0, 0);
    #pragma unroll
    for (int t = 0; t < 4; ++t)               // k 64..127: x
      acc = __builtin_amdgcn_mfma_f32_32x32x16_f16(
          W[4 + t], *reinterpret_cast<const f16x8*>(xhb + (t * 64 + l) * 8), acc, 0, 0, 0);
    #pragma unroll
    for (int t = 0; t < 4; ++t)               // k 128..191: agg(h)
      acc = __builtin_amdgcn_mfma_f32_32x32x16_f16(
          W[8 + t], *reinterpret_cast<const f16x8*>(aggb + ((4 + t) * 64 + l) * 8), acc, 0, 0, 0);
    #pragma unroll
    for (int t = 0; t < 4; ++t)               // k 192..255: h
      acc = __builtin_amdgcn_mfma_f32_32x32x16_f16(
          W[12 + t], *reinterpret_cast<const f16x8*>(xhb + ((4 + t) * 64 + l) * 8), acc, 0, 0, 0);

    // independent stream: aggregation for the other elem (fills MFMA shadow)
    if (tid < 384) agg_job(tid, ea, aggsrc);

    // lane-local epilogue: row l31 (<24), d = w*8 + 2u + hi
    if (l31 < 24) {
      unsigned short* xw = &XH[cur ^ 1][eg][0];
      const int wb = ((w >> 1) * 64 + l31 + ((w & 1) << 5)) * 8;
      #pragma unroll
      for (int u = 0; u < 4; ++u) {
        float cv = creg[eg * 4 + u];
        float I = sigm_(acc[4 * u + 0] + gwv[u] * cv);
        float F = sigm_(acc[4 * u + 1] + gwv[4 + u] * cv);
        float T = tanh_(acc[4 * u + 2]);
        float cn = F * cv + I * T;
        float O = sigm_(acc[4 * u + 3] + gwv[8 + u] * cn);
        float h = O * tanh_(cn);
        creg[eg * 4 + u] = cn;
        unsigned oh = pkrtz(O, h);            // lo = f16(O), hi = f16(h)
        int d7 = 2 * u + hi;
        xw[wb + d7]        = (unsigned short)oh;         // x slot
        xw[2048 + wb + d7] = (unsigned short)(oh >> 16); // h slot
        if (step >= 12)
          obuf[(size_t)((n2 + eg) * 12 + step - 12) * 1536 + l31 * 64 + w * 8 + d7] =
              (unsigned short)oh;
      }
    }
  };

  #pragma unroll 1
  for (int step = 0; step < 24; ++step) {
    if (step == 12) {                         // decode init: re-encode tgt[:,0]
      enc_to_x(tgt + (size_t)n2 * 864, tgt + (size_t)(n2 + 1) * 864, cur);
      __syncthreads();
      if (tid < 384) agg_job(tid, 0, cur);    // redo agg(e0) on fresh x
      __syncthreads();
    }
    phase(0, 1, cur, step);                   // GEMM/epi e0 || agg e1 (this step)
    __syncthreads();
    phase(1, 0, cur ^ 1, step);               // GEMM/epi e1 || agg e0 (next step)
    __syncthreads();
    cur ^= 1;
  }
}

// ---------------------------------------------------------------------------
// dec: out[row][e] = O[row,:] . decW[:,e] + db[e]; rows = n*12+ts.
// block: 32 rows, 4 waves K-split (384 each), 3 col-tiles, LDS reduce.
// ---------------------------------------------------------------------------
__global__ __launch_bounds__(256) void dec4_kernel(
    const unsigned short* __restrict__ obuf,
    const unsigned short* __restrict__ Bdec,
    const float* __restrict__ db,
    float* __restrict__ out)
{
  __shared__ float part[4 * 3 * 64 * 16];    // 48 KB
  const int tid = threadIdx.x;
  const int w = tid >> 6, l = tid & 63;
  const int l31 = l & 31, hi = l >> 5;
  const int r0 = blockIdx.x * 32;

  f32x16 a0, a1, a2;
  #pragma unroll
  for (int r = 0; r < 16; ++r) { a0[r] = 0.f; a1[r] = 0.f; a2[r] = 0.f; }

  const unsigned short* Ap = obuf + (size_t)(r0 + l31) * 1536 + hi * 8;
  #pragma unroll 4
  for (int tt = 0; tt < 24; ++tt) {
    int kt = w * 24 + tt;
    f16x8 av = *reinterpret_cast<const f16x8*>(Ap + kt * 16);
    f16x8 b0 = *reinterpret_cast<const f16x8*>(Bdec + ((0 * 96 + kt) * 64 + l) * 8);
    f16x8 b1 = *reinterpret_cast<const f16x8*>(Bdec + ((1 * 96 + kt) * 64 + l) * 8);
    f16x8 b2 = *reinterpret_cast<const f16x8*>(Bdec + ((2 * 96 + kt) * 64 + l) * 8);
    a0 = __builtin_amdgcn_mfma_f32_32x32x16_f16(av, b0, a0, 0, 0, 0);
    a1 = __builtin_amdgcn_mfma_f32_32x32x16_f16(av, b1, a1, 0, 0, 0);
    a2 = __builtin_amdgcn_mfma_f32_32x32x16_f16(av, b2, a2, 0, 0, 0);
  }
  #pragma unroll
  for (int r = 0; r < 16; ++r) {
    part[((w * 3 + 0) * 64 + l) * 16 + r] = a0[r];
    part[((w * 3 + 1) * 64 + l) * 16 + r] = a1[r];
    part[((w * 3 + 2) * 64 + l) * 16 + r] = a2[r];
  }
  __syncthreads();

  // reduce 4 K-partials; thread -> (row = tid>>3, e = (tid&7)*12 + 0..11)
  int row = tid >> 3;
  int hi2 = (row >> 2) & 1;
  int rr = 4 * (row >> 3) + (row & 3);
  #pragma unroll
  for (int ei = 0; ei < 12; ++ei) {
    int e = (tid & 7) * 12 + ei;
    if (e < 72) {
      int nt = e >> 5, e32 = e & 31;
      float s = db[e];
      #pragma unroll
      for (int w2 = 0; w2 < 4; ++w2)
        s += part[((w2 * 3 + nt) * 64 + e32 + 32 * hi2) * 16 + rr];
      out[(size_t)(r0 + row) * 72 + e] = s;
    }
  }
}

// ---------------------------------------------------------------------------
extern "C" void kernel_launch(void* const* d_in, const int* in_sizes, int n_in,
                              void* d_out, int out_size, void* d_ws, size_t ws_size,
                              hipStream_t stream) {
  const float* src  = (const float*)d_in[0];   // [1024,16,72]
  const float* tgt  = (const float*)d_in[1];   // [1024,12,72]
  const float* encW = (const float*)d_in[2];   // [3,64]
  const float* encb = (const float*)d_in[3];   // [64]
  const float* sWl  = (const float*)d_in[4];   // [8,64,64]
  const float* sbl  = (const float*)d_in[5];   // [8,64]
  const float* sWr  = (const float*)d_in[6];   // [8,64,64]
  const float* gw   = (const float*)d_in[7];   // [3,1,64]
  const float* gb   = (const float*)d_in[8];   // [4,1,64]
  const float* dW   = (const float*)d_in[9];   // [1536,72]
  const float* db   = (const float*)d_in[10];  // [72]
  float* out = (float*)d_out;

  unsigned short* obuf  = (unsigned short*)d_ws;        // 12288*1536 fp16
  unsigned short* Wfrag = obuf + (size_t)12288 * 1536;  // 65536 fp16
  unsigned short* Bdec  = Wfrag + 65536;                // 147456 fp16
  float*          biasv = (float*)(Bdec + 147456);      // 256 f32

  prep4_kernel<<<833, 256, 0, stream>>>(sWl, sbl, sWr, gb, dW, Wfrag, biasv, Bdec);
  mono9_kernel<<<512, 512, 0, stream>>>(src, tgt, encW, encb, gw, Wfrag, biasv, obuf);
  dec4_kernel<<<384, 256, 0, stream>>>(obuf, Bdec, db, out);
}